// Round 3
// baseline (415.430 us; speedup 1.0000x reference)
//
#include <hip/hip_runtime.h>

#define N_NODES 50000
#define E_EDGES 800000
#define IN_DIM  512
#define HID     256
#define OUTD    64

#define M_PAD   50048              // 391 * 128 (also 782 * 64)
#define SCAN_NB  49                // ceil(50000/1024)
#define PAD_N    (SCAN_NB * 1024)  // 50176

typedef unsigned int uint;
typedef unsigned short ushort;

using short8 = __attribute__((ext_vector_type(8))) short;
using f32x4  = __attribute__((ext_vector_type(4))) float;

__device__ __forceinline__ ushort f2bf(float f) {
    union { float f; uint u; } v; v.f = f;
    uint u = v.u;
    uint r = (u + 0x7FFFu + ((u >> 16) & 1u)) >> 16;  // RNE
    return (ushort)r;
}

__device__ __forceinline__ float bf2f(ushort h) {
    union { uint u; float f; } v; v.u = ((uint)h) << 16;
    return v.f;
}

// HW packed convert: dst = {bf16(a) | bf16(b)<<16}, RNE — 1 instr per 2 elems
// (identical rounding to the bit-twiddle; ~6x fewer VALU on the staging path)
__device__ __forceinline__ uint pk2(float a, float b) {
    uint r;
    asm("v_cvt_pk_bf16_f32 %0, %1, %2" : "=v"(r) : "v"(a), "v"(b));
    return r;
}

// ---------------------------------------------------------------- init
// fused: zero cnt[] + transpose/convert W1,W2 -> bf16 [N,K] (independent work)
__global__ __launch_bounds__(256) void init_k(const float* __restrict__ W1,
                                              const float* __restrict__ W2,
                                              ushort* __restrict__ W1t,
                                              ushort* __restrict__ W2t,
                                              int* __restrict__ cnt) {
    int i = blockIdx.x * 256 + threadIdx.x;
    if (i < PAD_N) cnt[i] = 0;
    const int N1 = IN_DIM * HID;  // 131072
    if (i < N1) {
        int n = i / IN_DIM;
        int k = i - n * IN_DIM;
        W1t[i] = f2bf(W1[(size_t)k * HID + n]);
    } else {
        int j = i - N1;
        if (j < HID * OUTD) {
            int n = j / HID;
            int k = j - n * HID;
            W2t[j] = f2bf(W2[(size_t)k * OUTD + n]);
        }
    }
}

// ---------------------------------------------------------------- CSR build
// hist + per-edge rank in one pass: rank[e] = position of edge within its row
__global__ void hist_k(const int* __restrict__ rows, int* __restrict__ cnt,
                       int* __restrict__ rank) {
    int e = blockIdx.x * 256 + threadIdx.x;
    if (e < E_EDGES) rank[e] = atomicAdd(&cnt[rows[e]], 1);
}

__global__ __launch_bounds__(256) void scan_part_k(const int* __restrict__ cnt,
                                                   int* __restrict__ bsum) {
    __shared__ int wsum[4];
    int tid  = threadIdx.x;
    int lane = tid & 63;
    int wave = tid >> 6;
    int4 q = *(const int4*)(cnt + blockIdx.x * 1024 + tid * 4);
    int s = q.x + q.y + q.z + q.w;
    #pragma unroll
    for (int d = 32; d > 0; d >>= 1) s += __shfl_down(s, d, 64);
    if (lane == 0) wsum[wave] = s;
    __syncthreads();
    if (tid == 0) bsum[blockIdx.x] = wsum[0] + wsum[1] + wsum[2] + wsum[3];
}

__global__ __launch_bounds__(64) void scan_bsum_k(const int* __restrict__ bsum,
                                                  int* __restrict__ boff) {
    int tid = threadIdx.x;
    int v = (tid < SCAN_NB) ? bsum[tid] : 0;
    int incl = v;
    #pragma unroll
    for (int d = 1; d < 64; d <<= 1) {
        int t = __shfl_up(incl, d, 64);
        if (tid >= d) incl += t;
    }
    if (tid < SCAN_NB) boff[tid] = incl - v;
}

__global__ __launch_bounds__(256) void scan_final_k(const int* __restrict__ cnt,
                                                    const int* __restrict__ boff,
                                                    int* __restrict__ row_ptr) {
    __shared__ int wsum[4];
    __shared__ int woff[4];
    int tid  = threadIdx.x;
    int lane = tid & 63;
    int wave = tid >> 6;
    int base = blockIdx.x * 1024 + tid * 4;
    int4 q = *(const int4*)(cnt + base);
    int s = q.x + q.y + q.z + q.w;
    int incl = s;
    #pragma unroll
    for (int d = 1; d < 64; d <<= 1) {
        int t = __shfl_up(incl, d, 64);
        if (lane >= d) incl += t;
    }
    if (lane == 63) wsum[wave] = incl;
    __syncthreads();
    if (tid == 0) {
        int run = 0;
        #pragma unroll
        for (int w = 0; w < 4; w++) { woff[w] = run; run += wsum[w]; }
    }
    __syncthreads();
    int off = boff[blockIdx.x] + woff[wave] + (incl - s);
    int4 o;
    o.x = off;
    o.y = off + q.x;
    o.z = o.y + q.y;
    o.w = o.z + q.z;
    *(int4*)(row_ptr + base) = o;
    if (blockIdx.x == 0 && tid == 0) row_ptr[N_NODES] = E_EDGES;
}

// atomic-free scatter: slot = row_ptr[row] + precomputed rank
__global__ void scatter_k(const int* __restrict__ rows, const int* __restrict__ cols,
                          const float* __restrict__ vals, const int* __restrict__ rptr,
                          const int* __restrict__ rank,
                          int* __restrict__ col_s, float* __restrict__ val_s) {
    int e = blockIdx.x * 256 + threadIdx.x;
    if (e < E_EDGES) {
        int p = rptr[rows[e]] + rank[e];
        col_s[p] = cols[e];
        val_s[p] = vals[e];
    }
}

// ---------------------------------------------------------------- GEMM bf16
// C[M,N](bf16) = A[M,K] * Bt[N,K](bf16 = B^T). A is fp32 (converted during
// staging, v_cvt_pk_bf16_f32) or bf16, per AF32. BK=64; 256 thr = 4 waves.
// L1: BM=64/BN=256 single N-pass (A staged+converted exactly once).
// T14 async-STAGE split: global loads of tile k+1 issued to REGISTERS before
// the MFMA phase of tile k; vmcnt-wait + convert + ds_write after the
// post-MFMA barrier. Round-1 lesson: NO occupancy floor in __launch_bounds__
// (a floor forced scratch spills: VGPR 112->84, +150MB scratch traffic).
// Prefetch footprint here: L1 ACH=2 -> +32 VGPR (~145 total), no spill.
template <bool AF32, int BM, int BN, int RW, int CW, int WM, int WN>
__global__ __launch_bounds__(256) void gemm_bf16(const float* __restrict__ Af,
                                                 const ushort* __restrict__ Ab,
                                                 const ushort* __restrict__ Bt,
                                                 ushort* __restrict__ C,
                                                 int M, int N, int K) {
    constexpr int BK  = 64;
    constexpr int LDT = 72;  // ushorts per LDS row (64 + 8 pad) = 144 B
    constexpr int ACH = (BM * BK / 8) / 256;
    constexpr int BCH = (BN * BK / 8) / 256;
    __shared__ ushort As[BM * LDT];
    __shared__ ushort Bs[BN * LDT];

    const int tid  = threadIdx.x;
    const int lane = tid & 63;
    const int wave = tid >> 6;
    const int quad = lane >> 4;
    const int l15  = lane & 15;

    const int col0 = blockIdx.x * BN;
    const int row0 = blockIdx.y * BM;

    const int wr = (wave % RW) * (WM * 16);
    const int wc = (wave / RW) * (WN * 16);

    f32x4 acc[WM][WN] = {};

    // prefetch registers (raw — conversion deferred to write phase)
    float4 pa_f[AF32 ? 2 * ACH : 1];
    uint4  pa_b[AF32 ? 1 : ACH];
    uint4  pb[BCH];

    auto load_tiles = [&](int k0) {
        #pragma unroll
        for (int p = 0; p < ACH; p++) {
            int c = tid + p * 256;
            int row = c >> 3, sub = c & 7;
            int gr = row0 + row;
            gr = gr < M ? gr : M - 1;
            if (AF32) {
                const float* pa = Af + (size_t)gr * K + k0 + sub * 8;
                pa_f[2 * p]     = *(const float4*)pa;
                pa_f[2 * p + 1] = *(const float4*)(pa + 4);
            } else {
                pa_b[p] = *(const uint4*)(Ab + (size_t)gr * K + k0 + sub * 8);
            }
        }
        #pragma unroll
        for (int p = 0; p < BCH; p++) {
            int c = tid + p * 256;
            int row = c >> 3, sub = c & 7;
            pb[p] = *(const uint4*)(Bt + (size_t)(col0 + row) * K + k0 + sub * 8);
        }
    };

    auto write_tiles = [&]() {
        #pragma unroll
        for (int p = 0; p < ACH; p++) {
            int c = tid + p * 256;
            int row = c >> 3, sub = c & 7;
            uint4 q;
            if (AF32) {
                float4 f0 = pa_f[2 * p];
                float4 f1 = pa_f[2 * p + 1];
                q.x = pk2(f0.x, f0.y);
                q.y = pk2(f0.z, f0.w);
                q.z = pk2(f1.x, f1.y);
                q.w = pk2(f1.z, f1.w);
            } else {
                q = pa_b[p];
            }
            *(uint4*)&As[row * LDT + sub * 8] = q;
        }
        #pragma unroll
        for (int p = 0; p < BCH; p++) {
            int c = tid + p * 256;
            int row = c >> 3, sub = c & 7;
            *(uint4*)&Bs[row * LDT + sub * 8] = pb[p];
        }
    };

    load_tiles(0);
    write_tiles();
    __syncthreads();

    for (int k0 = 0; k0 < K; k0 += BK) {
        const bool nxt = (k0 + BK) < K;
        if (nxt) load_tiles(k0 + BK);   // issue early: latency hides under MFMA
        #pragma unroll
        for (int kk = 0; kk < BK; kk += 32) {
            short8 af[WM], bf[WN];
            #pragma unroll
            for (int i = 0; i < WM; i++)
                af[i] = *(const short8*)&As[(wr + i * 16 + l15) * LDT + kk + quad * 8];
            #pragma unroll
            for (int j = 0; j < WN; j++)
                bf[j] = *(const short8*)&Bs[(wc + j * 16 + l15) * LDT + kk + quad * 8];
            #pragma unroll
            for (int i = 0; i < WM; i++)
                #pragma unroll
                for (int j = 0; j < WN; j++)
                    acc[i][j] = __builtin_amdgcn_mfma_f32_16x16x32_bf16(af[i], bf[j], acc[i][j], 0, 0, 0);
        }
        if (nxt) {
            __syncthreads();   // all waves done reading LDS
            write_tiles();     // vmcnt wait + convert lands here
            __syncthreads();   // writes visible
        }
    }

    // epilogue: C/D layout col=lane&15, row=quad*4+reg
    #pragma unroll
    for (int i = 0; i < WM; i++)
        #pragma unroll
        for (int j = 0; j < WN; j++)
            #pragma unroll
            for (int rr = 0; rr < 4; rr++) {
                int grow = row0 + wr + i * 16 + quad * 4 + rr;
                int gcol = col0 + wc + j * 16 + l15;
                if (grow < M) C[(size_t)grow * N + gcol] = f2bf(acc[i][j][rr]);
            }
}

// ---------------------------------------------------------------- SpMM 1
// wave per row; lane covers dims [lane*4, lane*4+4). Edge loop unrolled x4:
// 4 independent 512B gathers in flight to break the latency chain.
__global__ __launch_bounds__(256) void spmm1_k(const int* __restrict__ row_ptr,
                                               const int* __restrict__ col_s,
                                               const float* __restrict__ val_s,
                                               const ushort* __restrict__ h0,
                                               const float* __restrict__ b1,
                                               ushort* __restrict__ h) {
    int wave = threadIdx.x >> 6;
    int lane = threadIdx.x & 63;
    int r = blockIdx.x * 4 + wave;
    if (r >= N_NODES) return;
    int s = row_ptr[r];
    int e = row_ptr[r + 1];
    const ushort* hp = h0 + (size_t)lane * 4;
    float a0 = 0.f, a1 = 0.f, a2 = 0.f, a3 = 0.f;
    int i = s;
    for (; i + 4 <= e; i += 4) {
        int c0 = col_s[i];
        int c1 = col_s[i + 1];
        int c2 = col_s[i + 2];
        int c3 = col_s[i + 3];
        float v0 = val_s[i];
        float v1 = val_s[i + 1];
        float v2 = val_s[i + 2];
        float v3 = val_s[i + 3];
        ushort4 q0 = *(const ushort4*)(hp + (size_t)c0 * HID);
        ushort4 q1 = *(const ushort4*)(hp + (size_t)c1 * HID);
        ushort4 q2 = *(const ushort4*)(hp + (size_t)c2 * HID);
        ushort4 q3 = *(const ushort4*)(hp + (size_t)c3 * HID);
        a0 += v0 * bf2f(q0.x); a1 += v0 * bf2f(q0.y); a2 += v0 * bf2f(q0.z); a3 += v0 * bf2f(q0.w);
        a0 += v1 * bf2f(q1.x); a1 += v1 * bf2f(q1.y); a2 += v1 * bf2f(q1.z); a3 += v1 * bf2f(q1.w);
        a0 += v2 * bf2f(q2.x); a1 += v2 * bf2f(q2.y); a2 += v2 * bf2f(q2.z); a3 += v2 * bf2f(q2.w);
        a0 += v3 * bf2f(q3.x); a1 += v3 * bf2f(q3.y); a2 += v3 * bf2f(q3.z); a3 += v3 * bf2f(q3.w);
    }
    for (; i < e; i++) {
        int c = col_s[i];
        float v = val_s[i];
        ushort4 q = *(const ushort4*)(hp + (size_t)c * HID);
        a0 += v * bf2f(q.x); a1 += v * bf2f(q.y); a2 += v * bf2f(q.z); a3 += v * bf2f(q.w);
    }
    float4 bb = *(const float4*)(b1 + lane * 4);
    a0 += bb.x; a1 += bb.y; a2 += bb.z; a3 += bb.w;
    a0 = fmaxf(a0, 0.f); a1 = fmaxf(a1, 0.f); a2 = fmaxf(a2, 0.f); a3 = fmaxf(a3, 0.f);
    ushort4 o;
    o.x = f2bf(a0); o.y = f2bf(a1); o.z = f2bf(a2); o.w = f2bf(a3);
    *(ushort4*)(h + (size_t)r * HID + lane * 4) = o;
}

// ---------------------------------------------------------------- SpMM 2
__global__ __launch_bounds__(256) void spmm2_k(const int* __restrict__ row_ptr,
                                               const int* __restrict__ col_s,
                                               const float* __restrict__ val_s,
                                               const ushort* __restrict__ h2,
                                               const float* __restrict__ b2,
                                               float* __restrict__ out) {
    int wave = threadIdx.x >> 6;
    int lane = threadIdx.x & 63;
    int r = blockIdx.x * 4 + wave;
    if (r >= N_NODES) return;
    int s = row_ptr[r];
    int e = row_ptr[r + 1];
    int slot = lane >> 4;   // 0..3
    int dg   = lane & 15;   // dim group, 4 dims
    float a0 = 0.f, a1 = 0.f, a2 = 0.f, a3 = 0.f;
    const ushort* hp = h2 + (size_t)dg * 4;
    for (int i = s + slot; i < e; i += 4) {
        int c = col_s[i];
        float v = val_s[i];
        ushort4 q = *(const ushort4*)(hp + (size_t)c * OUTD);
        a0 += v * bf2f(q.x);
        a1 += v * bf2f(q.y);
        a2 += v * bf2f(q.z);
        a3 += v * bf2f(q.w);
    }
    #pragma unroll
    for (int m = 16; m < 64; m <<= 1) {
        a0 += __shfl_xor(a0, m, 64);
        a1 += __shfl_xor(a1, m, 64);
        a2 += __shfl_xor(a2, m, 64);
        a3 += __shfl_xor(a3, m, 64);
    }
    if (slot == 0) {
        float4 bb = *(const float4*)(b2 + dg * 4);
        float4 o;
        o.x = a0 + bb.x; o.y = a1 + bb.y; o.z = a2 + bb.z; o.w = a3 + bb.w;
        *(float4*)(out + (size_t)r * OUTD + dg * 4) = o;
    }
}

// ---------------------------------------------------------------- launch
extern "C" void kernel_launch(void* const* d_in, const int* in_sizes, int n_in,
                              void* d_out, int out_size, void* d_ws, size_t ws_size,
                              hipStream_t stream) {
    const float* x    = (const float*)d_in[0];
    const int*   rows = (const int*)d_in[1];
    const int*   cols = (const int*)d_in[2];
    const float* vals = (const float*)d_in[3];
    const float* W1   = (const float*)d_in[4];
    const float* b1   = (const float*)d_in[5];
    const float* W2   = (const float*)d_in[6];
    const float* b2   = (const float*)d_in[7];
    float* out = (float*)d_out;

    char* ws = (char*)d_ws;
    size_t off = 0;
    auto alloc = [&](size_t bytes) {
        char* p = ws + off;
        off = (off + bytes + 255) & ~(size_t)255;
        return p;
    };
    ushort* w1t   = (ushort*)alloc((size_t)HID * IN_DIM * 2);
    ushort* w2t   = (ushort*)alloc((size_t)OUTD * HID * 2);
    ushort* h0    = (ushort*)alloc((size_t)N_NODES * HID * 2);
    ushort* h     = (ushort*)alloc((size_t)M_PAD * HID * 2);     // padded rows
    ushort* h2    = (ushort*)alloc((size_t)N_NODES * OUTD * 2);
    int*    cnt   = (int*)alloc((PAD_N) * 4);
    int*    rptr  = (int*)alloc((PAD_N + 1) * 4);
    int*    bsum  = (int*)alloc(SCAN_NB * 4);
    int*    boff  = (int*)alloc(SCAN_NB * 4);
    int*    rank  = (int*)alloc((size_t)E_EDGES * 4);
    int*    col_s = (int*)alloc((size_t)E_EDGES * 4);
    float*  val_s = (float*)alloc((size_t)E_EDGES * 4);

    // init: zero cnt + weight transpose/convert (fused, independent work)
    {
        const int work = IN_DIM * HID + HID * OUTD;  // 147456 > PAD_N
        init_k<<<(work + 255) / 256, 256, 0, stream>>>(W1, W2, w1t, w2t, cnt);
    }
    // CSR build (reused by both SpMMs)
    hist_k<<<(E_EDGES + 255) / 256, 256, 0, stream>>>(rows, cnt, rank);
    scan_part_k<<<SCAN_NB, 256, 0, stream>>>(cnt, bsum);
    scan_bsum_k<<<1, 64, 0, stream>>>(bsum, boff);
    scan_final_k<<<SCAN_NB, 256, 0, stream>>>(cnt, boff, rptr);
    scatter_k<<<(E_EDGES + 255) / 256, 256, 0, stream>>>(rows, cols, vals, rptr, rank, col_s, val_s);

    // layer 1: h0 = x @ W1, BM=64 x BN=256 single N-pass (A converted once)
    gemm_bf16<true, 64, 256, 1, 4, 4, 4><<<dim3(HID / 256, M_PAD / 64), 256, 0, stream>>>(
        x, nullptr, w1t, h0, N_NODES, HID, IN_DIM);
    spmm1_k<<<(N_NODES + 3) / 4, 256, 0, stream>>>(rptr, col_s, val_s, h0, b1, h);

    // layer 2
    gemm_bf16<false, 128, 64, 4, 1, 2, 4><<<dim3(OUTD / 64, M_PAD / 128), 256, 0, stream>>>(
        nullptr, h, w2t, h2, N_NODES, OUTD, HID);
    spmm2_k<<<(N_NODES + 3) / 4, 256, 0, stream>>>(rptr, col_s, val_s, h2, b2, out);
}

// Round 4
// 400.949 us; speedup vs baseline: 1.0361x; 1.0361x over previous
//
#include <hip/hip_runtime.h>

#define N_NODES 50000
#define E_EDGES 800000
#define IN_DIM  512
#define HID     256
#define OUTD    64

#define M_PAD   50048              // 391 * 128 (also 782 * 64)
#define SCAN_NB  49                // ceil(50000/1024)
#define PAD_N    (SCAN_NB * 1024)  // 50176

typedef unsigned int uint;
typedef unsigned short ushort;

using short8 = __attribute__((ext_vector_type(8))) short;
using f32x4  = __attribute__((ext_vector_type(4))) float;

__device__ __forceinline__ ushort f2bf(float f) {
    union { float f; uint u; } v; v.f = f;
    uint u = v.u;
    uint r = (u + 0x7FFFu + ((u >> 16) & 1u)) >> 16;  // RNE
    return (ushort)r;
}

__device__ __forceinline__ float bf2f(ushort h) {
    union { uint u; float f; } v; v.u = ((uint)h) << 16;
    return v.f;
}

// HW packed convert: dst = {bf16(a) | bf16(b)<<16}, RNE — 1 instr per 2 elems
__device__ __forceinline__ uint pk2(float a, float b) {
    uint r;
    asm("v_cvt_pk_bf16_f32 %0, %1, %2" : "=v"(r) : "v"(a), "v"(b));
    return r;
}

// ---------------------------------------------------------------- init
// fused: zero cnt[] + transpose/convert W1,W2 -> bf16 [N,K] (independent work)
__global__ __launch_bounds__(256) void init_k(const float* __restrict__ W1,
                                              const float* __restrict__ W2,
                                              ushort* __restrict__ W1t,
                                              ushort* __restrict__ W2t,
                                              int* __restrict__ cnt) {
    int i = blockIdx.x * 256 + threadIdx.x;
    if (i < PAD_N) cnt[i] = 0;
    const int N1 = IN_DIM * HID;  // 131072
    if (i < N1) {
        int n = i / IN_DIM;
        int k = i - n * IN_DIM;
        W1t[i] = f2bf(W1[(size_t)k * HID + n]);
    } else {
        int j = i - N1;
        if (j < HID * OUTD) {
            int n = j / HID;
            int k = j - n * HID;
            W2t[j] = f2bf(W2[(size_t)k * OUTD + n]);
        }
    }
}

// ---------------------------------------------------------------- CSR build
// hist + per-edge rank in one pass: rank[e] = position of edge within its row
__global__ void hist_k(const int* __restrict__ rows, int* __restrict__ cnt,
                       int* __restrict__ rank) {
    int e = blockIdx.x * 256 + threadIdx.x;
    if (e < E_EDGES) rank[e] = atomicAdd(&cnt[rows[e]], 1);
}

__global__ __launch_bounds__(256) void scan_part_k(const int* __restrict__ cnt,
                                                   int* __restrict__ bsum) {
    __shared__ int wsum[4];
    int tid  = threadIdx.x;
    int lane = tid & 63;
    int wave = tid >> 6;
    int4 q = *(const int4*)(cnt + blockIdx.x * 1024 + tid * 4);
    int s = q.x + q.y + q.z + q.w;
    #pragma unroll
    for (int d = 32; d > 0; d >>= 1) s += __shfl_down(s, d, 64);
    if (lane == 0) wsum[wave] = s;
    __syncthreads();
    if (tid == 0) bsum[blockIdx.x] = wsum[0] + wsum[1] + wsum[2] + wsum[3];
}

__global__ __launch_bounds__(64) void scan_bsum_k(const int* __restrict__ bsum,
                                                  int* __restrict__ boff) {
    int tid = threadIdx.x;
    int v = (tid < SCAN_NB) ? bsum[tid] : 0;
    int incl = v;
    #pragma unroll
    for (int d = 1; d < 64; d <<= 1) {
        int t = __shfl_up(incl, d, 64);
        if (tid >= d) incl += t;
    }
    if (tid < SCAN_NB) boff[tid] = incl - v;
}

__global__ __launch_bounds__(256) void scan_final_k(const int* __restrict__ cnt,
                                                    const int* __restrict__ boff,
                                                    int* __restrict__ row_ptr) {
    __shared__ int wsum[4];
    __shared__ int woff[4];
    int tid  = threadIdx.x;
    int lane = tid & 63;
    int wave = tid >> 6;
    int base = blockIdx.x * 1024 + tid * 4;
    int4 q = *(const int4*)(cnt + base);
    int s = q.x + q.y + q.z + q.w;
    int incl = s;
    #pragma unroll
    for (int d = 1; d < 64; d <<= 1) {
        int t = __shfl_up(incl, d, 64);
        if (lane >= d) incl += t;
    }
    if (lane == 63) wsum[wave] = incl;
    __syncthreads();
    if (tid == 0) {
        int run = 0;
        #pragma unroll
        for (int w = 0; w < 4; w++) { woff[w] = run; run += wsum[w]; }
    }
    __syncthreads();
    int off = boff[blockIdx.x] + woff[wave] + (incl - s);
    int4 o;
    o.x = off;
    o.y = off + q.x;
    o.z = o.y + q.y;
    o.w = o.z + q.z;
    *(int4*)(row_ptr + base) = o;
    if (blockIdx.x == 0 && tid == 0) row_ptr[N_NODES] = E_EDGES;
}

// atomic-free scatter: slot = row_ptr[row] + precomputed rank
__global__ void scatter_k(const int* __restrict__ rows, const int* __restrict__ cols,
                          const float* __restrict__ vals, const int* __restrict__ rptr,
                          const int* __restrict__ rank,
                          int* __restrict__ col_s, float* __restrict__ val_s) {
    int e = blockIdx.x * 256 + threadIdx.x;
    if (e < E_EDGES) {
        int p = rptr[rows[e]] + rank[e];
        col_s[p] = cols[e];
        val_s[p] = vals[e];
    }
}

// ---------------------------------------------------------------- GEMM bf16
// C[M,N](bf16) = A[M,K] * Bt[N,K](bf16 = B^T). T14 prefetch, 3rd attempt:
// rounds 1/3 spilled because prefetch arrays were captured BY REFERENCE in
// lambdas (address taken -> alloca -> scratch; VGPR 84/124 + 120-150 MB/dispatch
// scratch WRITE_SIZE). Fix by construction: macros (textual inline), arrays
// declared INSIDE the loop body (intra-iteration liveness only), peeled loop
// (no conditional prefetch). All indices static under unroll -> SSA -> VGPRs.
template <bool AF32, int BM, int BN, int RW, int CW, int WM, int WN>
__global__ __launch_bounds__(256) void gemm_bf16(const float* __restrict__ Af,
                                                 const ushort* __restrict__ Ab,
                                                 const ushort* __restrict__ Bt,
                                                 ushort* __restrict__ C,
                                                 int M, int N, int K) {
    constexpr int BK  = 64;
    constexpr int LDT = 72;  // ushorts per LDS row (64 + 8 pad) = 144 B
    constexpr int ACH = (BM * BK / 8) / 256;
    constexpr int BCH = (BN * BK / 8) / 256;
    __shared__ ushort As[BM * LDT];
    __shared__ ushort Bs[BN * LDT];

    const int tid  = threadIdx.x;
    const int lane = tid & 63;
    const int wave = tid >> 6;
    const int quad = lane >> 4;
    const int l15  = lane & 15;

    const int col0 = blockIdx.x * BN;
    const int row0 = blockIdx.y * BM;

    const int wr = (wave % RW) * (WM * 16);
    const int wc = (wave / RW) * (WN * 16);

    f32x4 acc[WM][WN] = {};

#define G_LOAD(KOFF)                                                          \
    _Pragma("unroll")                                                         \
    for (int p = 0; p < ACH; p++) {                                           \
        int c = tid + p * 256;                                                \
        int row = c >> 3, sub = c & 7;                                        \
        int gr = row0 + row;                                                  \
        gr = gr < M ? gr : M - 1;                                             \
        if constexpr (AF32) {                                                 \
            const float* pa = Af + (size_t)gr * K + (KOFF) + sub * 8;         \
            pf[2 * p]     = *(const float4*)pa;                               \
            pf[2 * p + 1] = *(const float4*)(pa + 4);                         \
        } else {                                                              \
            pba[p] = *(const uint4*)(Ab + (size_t)gr * K + (KOFF) + sub * 8); \
        }                                                                     \
    }                                                                         \
    _Pragma("unroll")                                                         \
    for (int p = 0; p < BCH; p++) {                                           \
        int c = tid + p * 256;                                                \
        int row = c >> 3, sub = c & 7;                                        \
        pbb[p] = *(const uint4*)(Bt + (size_t)(col0 + row) * K + (KOFF) + sub * 8); \
    }

#define G_WRITE()                                                             \
    _Pragma("unroll")                                                         \
    for (int p = 0; p < ACH; p++) {                                           \
        int c = tid + p * 256;                                                \
        int row = c >> 3, sub = c & 7;                                        \
        uint4 q;                                                              \
        if constexpr (AF32) {                                                 \
            float4 f0 = pf[2 * p];                                            \
            float4 f1 = pf[2 * p + 1];                                        \
            q.x = pk2(f0.x, f0.y);                                            \
            q.y = pk2(f0.z, f0.w);                                            \
            q.z = pk2(f1.x, f1.y);                                            \
            q.w = pk2(f1.z, f1.w);                                            \
        } else {                                                              \
            q = pba[p];                                                       \
        }                                                                     \
        *(uint4*)&As[row * LDT + sub * 8] = q;                                \
    }                                                                         \
    _Pragma("unroll")                                                         \
    for (int p = 0; p < BCH; p++) {                                           \
        int c = tid + p * 256;                                                \
        int row = c >> 3, sub = c & 7;                                        \
        *(uint4*)&Bs[row * LDT + sub * 8] = pbb[p];                           \
    }

#define G_COMPUTE()                                                           \
    _Pragma("unroll")                                                         \
    for (int kk = 0; kk < BK; kk += 32) {                                     \
        short8 af[WM], bf[WN];                                                \
        _Pragma("unroll")                                                     \
        for (int i = 0; i < WM; i++)                                          \
            af[i] = *(const short8*)&As[(wr + i * 16 + l15) * LDT + kk + quad * 8]; \
        _Pragma("unroll")                                                     \
        for (int j = 0; j < WN; j++)                                          \
            bf[j] = *(const short8*)&Bs[(wc + j * 16 + l15) * LDT + kk + quad * 8]; \
        _Pragma("unroll")                                                     \
        for (int i = 0; i < WM; i++)                                          \
            _Pragma("unroll")                                                 \
            for (int j = 0; j < WN; j++)                                      \
                acc[i][j] = __builtin_amdgcn_mfma_f32_16x16x32_bf16(af[i], bf[j], acc[i][j], 0, 0, 0); \
    }

    // prologue: stage tile 0
    {
        float4 pf[AF32 ? 2 * ACH : 1];
        uint4  pba[AF32 ? 1 : ACH];
        uint4  pbb[BCH];
        G_LOAD(0)
        G_WRITE()
    }
    __syncthreads();

    int k0 = 0;
    for (; k0 + BK < K; k0 += BK) {
        float4 pf[AF32 ? 2 * ACH : 1];
        uint4  pba[AF32 ? 1 : ACH];
        uint4  pbb[BCH];
        G_LOAD(k0 + BK)     // issue next-tile loads; latency hides under MFMA
        G_COMPUTE()
        __syncthreads();    // all waves done reading LDS
        G_WRITE()           // vmcnt wait + convert lands here
        __syncthreads();    // writes visible
    }
    G_COMPUTE()             // last tile (no prefetch)

#undef G_LOAD
#undef G_WRITE
#undef G_COMPUTE

    // epilogue: C/D layout col=lane&15, row=quad*4+reg
    #pragma unroll
    for (int i = 0; i < WM; i++)
        #pragma unroll
        for (int j = 0; j < WN; j++)
            #pragma unroll
            for (int rr = 0; rr < 4; rr++) {
                int grow = row0 + wr + i * 16 + quad * 4 + rr;
                int gcol = col0 + wc + j * 16 + l15;
                if (grow < M) C[(size_t)grow * N + gcol] = f2bf(acc[i][j][rr]);
            }
}

// ---------------------------------------------------------------- SpMM 1
// wave per row; lane covers dims [lane*4, lane*4+4). Edge loop unrolled x4:
// 4 independent 512B gathers in flight to break the latency chain.
__global__ __launch_bounds__(256) void spmm1_k(const int* __restrict__ row_ptr,
                                               const int* __restrict__ col_s,
                                               const float* __restrict__ val_s,
                                               const ushort* __restrict__ h0,
                                               const float* __restrict__ b1,
                                               ushort* __restrict__ h) {
    int wave = threadIdx.x >> 6;
    int lane = threadIdx.x & 63;
    int r = blockIdx.x * 4 + wave;
    if (r >= N_NODES) return;
    int s = row_ptr[r];
    int e = row_ptr[r + 1];
    const ushort* hp = h0 + (size_t)lane * 4;
    float a0 = 0.f, a1 = 0.f, a2 = 0.f, a3 = 0.f;
    int i = s;
    for (; i + 4 <= e; i += 4) {
        int c0 = col_s[i];
        int c1 = col_s[i + 1];
        int c2 = col_s[i + 2];
        int c3 = col_s[i + 3];
        float v0 = val_s[i];
        float v1 = val_s[i + 1];
        float v2 = val_s[i + 2];
        float v3 = val_s[i + 3];
        ushort4 q0 = *(const ushort4*)(hp + (size_t)c0 * HID);
        ushort4 q1 = *(const ushort4*)(hp + (size_t)c1 * HID);
        ushort4 q2 = *(const ushort4*)(hp + (size_t)c2 * HID);
        ushort4 q3 = *(const ushort4*)(hp + (size_t)c3 * HID);
        a0 += v0 * bf2f(q0.x); a1 += v0 * bf2f(q0.y); a2 += v0 * bf2f(q0.z); a3 += v0 * bf2f(q0.w);
        a0 += v1 * bf2f(q1.x); a1 += v1 * bf2f(q1.y); a2 += v1 * bf2f(q1.z); a3 += v1 * bf2f(q1.w);
        a0 += v2 * bf2f(q2.x); a1 += v2 * bf2f(q2.y); a2 += v2 * bf2f(q2.z); a3 += v2 * bf2f(q2.w);
        a0 += v3 * bf2f(q3.x); a1 += v3 * bf2f(q3.y); a2 += v3 * bf2f(q3.z); a3 += v3 * bf2f(q3.w);
    }
    for (; i < e; i++) {
        int c = col_s[i];
        float v = val_s[i];
        ushort4 q = *(const ushort4*)(hp + (size_t)c * HID);
        a0 += v * bf2f(q.x); a1 += v * bf2f(q.y); a2 += v * bf2f(q.z); a3 += v * bf2f(q.w);
    }
    float4 bb = *(const float4*)(b1 + lane * 4);
    a0 += bb.x; a1 += bb.y; a2 += bb.z; a3 += bb.w;
    a0 = fmaxf(a0, 0.f); a1 = fmaxf(a1, 0.f); a2 = fmaxf(a2, 0.f); a3 = fmaxf(a3, 0.f);
    ushort4 o;
    o.x = f2bf(a0); o.y = f2bf(a1); o.z = f2bf(a2); o.w = f2bf(a3);
    *(ushort4*)(h + (size_t)r * HID + lane * 4) = o;
}

// ---------------------------------------------------------------- SpMM 2
__global__ __launch_bounds__(256) void spmm2_k(const int* __restrict__ row_ptr,
                                               const int* __restrict__ col_s,
                                               const float* __restrict__ val_s,
                                               const ushort* __restrict__ h2,
                                               const float* __restrict__ b2,
                                               float* __restrict__ out) {
    int wave = threadIdx.x >> 6;
    int lane = threadIdx.x & 63;
    int r = blockIdx.x * 4 + wave;
    if (r >= N_NODES) return;
    int s = row_ptr[r];
    int e = row_ptr[r + 1];
    int slot = lane >> 4;   // 0..3
    int dg   = lane & 15;   // dim group, 4 dims
    float a0 = 0.f, a1 = 0.f, a2 = 0.f, a3 = 0.f;
    const ushort* hp = h2 + (size_t)dg * 4;
    for (int i = s + slot; i < e; i += 4) {
        int c = col_s[i];
        float v = val_s[i];
        ushort4 q = *(const ushort4*)(hp + (size_t)c * OUTD);
        a0 += v * bf2f(q.x);
        a1 += v * bf2f(q.y);
        a2 += v * bf2f(q.z);
        a3 += v * bf2f(q.w);
    }
    #pragma unroll
    for (int m = 16; m < 64; m <<= 1) {
        a0 += __shfl_xor(a0, m, 64);
        a1 += __shfl_xor(a1, m, 64);
        a2 += __shfl_xor(a2, m, 64);
        a3 += __shfl_xor(a3, m, 64);
    }
    if (slot == 0) {
        float4 bb = *(const float4*)(b2 + dg * 4);
        float4 o;
        o.x = a0 + bb.x; o.y = a1 + bb.y; o.z = a2 + bb.z; o.w = a3 + bb.w;
        *(float4*)(out + (size_t)r * OUTD + dg * 4) = o;
    }
}

// ---------------------------------------------------------------- launch
extern "C" void kernel_launch(void* const* d_in, const int* in_sizes, int n_in,
                              void* d_out, int out_size, void* d_ws, size_t ws_size,
                              hipStream_t stream) {
    const float* x    = (const float*)d_in[0];
    const int*   rows = (const int*)d_in[1];
    const int*   cols = (const int*)d_in[2];
    const float* vals = (const float*)d_in[3];
    const float* W1   = (const float*)d_in[4];
    const float* b1   = (const float*)d_in[5];
    const float* W2   = (const float*)d_in[6];
    const float* b2   = (const float*)d_in[7];
    float* out = (float*)d_out;

    char* ws = (char*)d_ws;
    size_t off = 0;
    auto alloc = [&](size_t bytes) {
        char* p = ws + off;
        off = (off + bytes + 255) & ~(size_t)255;
        return p;
    };
    ushort* w1t   = (ushort*)alloc((size_t)HID * IN_DIM * 2);
    ushort* w2t   = (ushort*)alloc((size_t)OUTD * HID * 2);
    ushort* h0    = (ushort*)alloc((size_t)N_NODES * HID * 2);
    ushort* h     = (ushort*)alloc((size_t)M_PAD * HID * 2);     // padded rows
    ushort* h2    = (ushort*)alloc((size_t)N_NODES * OUTD * 2);
    int*    cnt   = (int*)alloc((PAD_N) * 4);
    int*    rptr  = (int*)alloc((PAD_N + 1) * 4);
    int*    bsum  = (int*)alloc(SCAN_NB * 4);
    int*    boff  = (int*)alloc(SCAN_NB * 4);
    int*    rank  = (int*)alloc((size_t)E_EDGES * 4);
    int*    col_s = (int*)alloc((size_t)E_EDGES * 4);
    float*  val_s = (float*)alloc((size_t)E_EDGES * 4);

    // init: zero cnt + weight transpose/convert (fused, independent work)
    {
        const int work = IN_DIM * HID + HID * OUTD;  // 147456 > PAD_N
        init_k<<<(work + 255) / 256, 256, 0, stream>>>(W1, W2, w1t, w2t, cnt);
    }
    // CSR build (reused by both SpMMs)
    hist_k<<<(E_EDGES + 255) / 256, 256, 0, stream>>>(rows, cnt, rank);
    scan_part_k<<<SCAN_NB, 256, 0, stream>>>(cnt, bsum);
    scan_bsum_k<<<1, 64, 0, stream>>>(bsum, boff);
    scan_final_k<<<SCAN_NB, 256, 0, stream>>>(cnt, boff, rptr);
    scatter_k<<<(E_EDGES + 255) / 256, 256, 0, stream>>>(rows, cols, vals, rptr, rank, col_s, val_s);

    // layer 1: h0 = x @ W1, BM=64 x BN=256 single N-pass (A converted once)
    gemm_bf16<true, 64, 256, 1, 4, 4, 4><<<dim3(HID / 256, M_PAD / 64), 256, 0, stream>>>(
        x, nullptr, w1t, h0, N_NODES, HID, IN_DIM);
    spmm1_k<<<(N_NODES + 3) / 4, 256, 0, stream>>>(rptr, col_s, val_s, h0, b1, h);

    // layer 2
    gemm_bf16<false, 128, 64, 4, 1, 2, 4><<<dim3(OUTD / 64, M_PAD / 128), 256, 0, stream>>>(
        nullptr, h, w2t, h2, N_NODES, OUTD, HID);
    spmm2_k<<<(N_NODES + 3) / 4, 256, 0, stream>>>(rptr, col_s, val_s, h2, b2, out);
}

// Round 5
// 358.006 us; speedup vs baseline: 1.1604x; 1.1199x over previous
//
#include <hip/hip_runtime.h>

#define N_NODES 50000
#define E_EDGES 800000
#define IN_DIM  512
#define HID     256
#define OUTD    64

#define M_PAD   50048              // 391 * 128 (also 782 * 64)
#define SCAN_NB  49                // ceil(50000/1024)
#define PAD_N    (SCAN_NB * 1024)  // 50176

typedef unsigned int uint;
typedef unsigned short ushort;

using short8 = __attribute__((ext_vector_type(8))) short;
using f32x4  = __attribute__((ext_vector_type(4))) float;

__device__ __forceinline__ ushort f2bf(float f) {
    union { float f; uint u; } v; v.f = f;
    uint u = v.u;
    uint r = (u + 0x7FFFu + ((u >> 16) & 1u)) >> 16;  // RNE
    return (ushort)r;
}

__device__ __forceinline__ float bf2f(ushort h) {
    union { uint u; float f; } v; v.u = ((uint)h) << 16;
    return v.f;
}

// HW packed convert: dst = {bf16(a) | bf16(b)<<16}, RNE — 1 instr per 2 elems
__device__ __forceinline__ uint pk2(float a, float b) {
    uint r;
    asm("v_cvt_pk_bf16_f32 %0, %1, %2" : "=v"(r) : "v"(a), "v"(b));
    return r;
}

// 16B global -> LDS DMA. LDS dest is wave-uniform base + lane*16 (HW rule);
// global source is per-lane (pre-swizzled-source pattern).
__device__ __forceinline__ void gld_lds16(const ushort* g, ushort* l) {
    __builtin_amdgcn_global_load_lds(
        (const __attribute__((address_space(1))) unsigned int*)g,
        (__attribute__((address_space(3))) unsigned int*)l, 16, 0, 0);
}

// ---------------------------------------------------------------- init
// fused: zero cnt[] + transpose/convert W1,W2 -> bf16 [N,K] (independent work)
__global__ __launch_bounds__(256) void init_k(const float* __restrict__ W1,
                                              const float* __restrict__ W2,
                                              ushort* __restrict__ W1t,
                                              ushort* __restrict__ W2t,
                                              int* __restrict__ cnt) {
    int i = blockIdx.x * 256 + threadIdx.x;
    if (i < PAD_N) cnt[i] = 0;
    const int N1 = IN_DIM * HID;  // 131072
    if (i < N1) {
        int n = i / IN_DIM;
        int k = i - n * IN_DIM;
        W1t[i] = f2bf(W1[(size_t)k * HID + n]);
    } else {
        int j = i - N1;
        if (j < HID * OUTD) {
            int n = j / HID;
            int k = j - n * HID;
            W2t[j] = f2bf(W2[(size_t)k * OUTD + n]);
        }
    }
}

// ---------------------------------------------------------------- CSR build
// hist + per-edge rank in one pass: rank[e] = position of edge within its row
__global__ void hist_k(const int* __restrict__ rows, int* __restrict__ cnt,
                       int* __restrict__ rank) {
    int e = blockIdx.x * 256 + threadIdx.x;
    if (e < E_EDGES) rank[e] = atomicAdd(&cnt[rows[e]], 1);
}

__global__ __launch_bounds__(256) void scan_part_k(const int* __restrict__ cnt,
                                                   int* __restrict__ bsum) {
    __shared__ int wsum[4];
    int tid  = threadIdx.x;
    int lane = tid & 63;
    int wave = tid >> 6;
    int4 q = *(const int4*)(cnt + blockIdx.x * 1024 + tid * 4);
    int s = q.x + q.y + q.z + q.w;
    #pragma unroll
    for (int d = 32; d > 0; d >>= 1) s += __shfl_down(s, d, 64);
    if (lane == 0) wsum[wave] = s;
    __syncthreads();
    if (tid == 0) bsum[blockIdx.x] = wsum[0] + wsum[1] + wsum[2] + wsum[3];
}

__global__ __launch_bounds__(64) void scan_bsum_k(const int* __restrict__ bsum,
                                                  int* __restrict__ boff) {
    int tid = threadIdx.x;
    int v = (tid < SCAN_NB) ? bsum[tid] : 0;
    int incl = v;
    #pragma unroll
    for (int d = 1; d < 64; d <<= 1) {
        int t = __shfl_up(incl, d, 64);
        if (tid >= d) incl += t;
    }
    if (tid < SCAN_NB) boff[tid] = incl - v;
}

__global__ __launch_bounds__(256) void scan_final_k(const int* __restrict__ cnt,
                                                    const int* __restrict__ boff,
                                                    int* __restrict__ row_ptr) {
    __shared__ int wsum[4];
    __shared__ int woff[4];
    int tid  = threadIdx.x;
    int lane = tid & 63;
    int wave = tid >> 6;
    int base = blockIdx.x * 1024 + tid * 4;
    int4 q = *(const int4*)(cnt + base);
    int s = q.x + q.y + q.z + q.w;
    int incl = s;
    #pragma unroll
    for (int d = 1; d < 64; d <<= 1) {
        int t = __shfl_up(incl, d, 64);
        if (lane >= d) incl += t;
    }
    if (lane == 63) wsum[wave] = incl;
    __syncthreads();
    if (tid == 0) {
        int run = 0;
        #pragma unroll
        for (int w = 0; w < 4; w++) { woff[w] = run; run += wsum[w]; }
    }
    __syncthreads();
    int off = boff[blockIdx.x] + woff[wave] + (incl - s);
    int4 o;
    o.x = off;
    o.y = off + q.x;
    o.z = o.y + q.y;
    o.w = o.z + q.z;
    *(int4*)(row_ptr + base) = o;
    if (blockIdx.x == 0 && tid == 0) row_ptr[N_NODES] = E_EDGES;
}

// atomic-free scatter: slot = row_ptr[row] + precomputed rank
__global__ void scatter_k(const int* __restrict__ rows, const int* __restrict__ cols,
                          const float* __restrict__ vals, const int* __restrict__ rptr,
                          const int* __restrict__ rank,
                          int* __restrict__ col_s, float* __restrict__ val_s) {
    int e = blockIdx.x * 256 + threadIdx.x;
    if (e < E_EDGES) {
        int p = rptr[rows[e]] + rank[e];
        col_s[p] = cols[e];
        val_s[p] = vals[e];
    }
}

// ---------------------------------------------------------------- GEMM bf16
// C[M,N](bf16) = A[M,K] * Bt[N,K](bf16 = B^T). Synchronous staging (the
// round-2 proven structure — register prefetch spilled in 3 attempts and is
// retired). New: all preconverted-bf16 tiles staged via global_load_lds
// width=16 (B both layers; A for layer 2). DMA forces a LINEAR LDS dest, so
// bank conflicts are handled by the both-sides XOR swizzle (rule #21):
//   store: lane's source col-group = (lane&7) ^ ((lane>>3)&7)
//   read:  slot = col_group ^ (row&7)   (row&7 == lane&7 on the read path)
// Conflict profile identical to the old +8-pad layout (2-way in quad).
// L1's A stays fp32->bf16 register convert path (padded rows, clamp for x).
template <bool AF32, int BM, int BN, int RW, int CW, int WM, int WN>
__global__ __launch_bounds__(256) void gemm_bf16(const float* __restrict__ Af,
                                                 const ushort* __restrict__ Ab,
                                                 const ushort* __restrict__ Bt,
                                                 ushort* __restrict__ C,
                                                 int M, int N, int K) {
    constexpr int BK   = 64;
    constexpr int LDTA = AF32 ? 72 : 64;      // A rows: padded (reg) / linear (DMA)
    constexpr int ACH  = (BM * BK / 8) / 256; // reg-path chunks per thread
    __shared__ ushort As[BM * LDTA];
    __shared__ ushort Bs[BN * 64];

    const int tid  = threadIdx.x;
    const int lane = tid & 63;
    const int wave = tid >> 6;
    const int quad = lane >> 4;
    const int l15  = lane & 15;
    const int l7   = lane & 7;

    const int col0 = blockIdx.x * BN;
    const int row0 = blockIdx.y * BM;

    const int wr = (wave % RW) * (WM * 16);
    const int wc = (wave / RW) * (WN * 16);

    const int swz    = (l7 ^ ((lane >> 3) & 7)) << 3;  // source col offset (ushorts)
    const int subrow = lane >> 3;                      // row within 8-row chunk

    f32x4 acc[WM][WN] = {};

    for (int k0 = 0; k0 < K; k0 += BK) {
        // ---- B tile: DMA, fire-and-forget until barrier's vmcnt drain
        #pragma unroll
        for (int p = 0; p < BN / 32; p++) {
            int ch  = wave * (BN / 32) + p;
            int row = ch * 8 + subrow;
            gld_lds16(Bt + (size_t)(col0 + row) * K + k0 + swz, &Bs[ch * 512]);
        }
        // ---- A tile
        if constexpr (AF32) {
            #pragma unroll
            for (int p = 0; p < ACH; p++) {
                int c = tid + p * 256;
                int row = c >> 3, sub = c & 7;
                int gr = row0 + row;
                gr = gr < M ? gr : M - 1;           // x has exactly M rows
                const float* pa = Af + (size_t)gr * K + k0 + sub * 8;
                float4 f0 = *(const float4*)pa;
                float4 f1 = *(const float4*)(pa + 4);
                uint4 q;
                q.x = pk2(f0.x, f0.y);
                q.y = pk2(f0.z, f0.w);
                q.z = pk2(f1.x, f1.y);
                q.w = pk2(f1.z, f1.w);
                *(uint4*)&As[row * LDTA + sub * 8] = q;
            }
        } else {
            // h buffer has M_PAD rows: always in-bounds, no clamp needed
            #pragma unroll
            for (int p = 0; p < BM / 32; p++) {
                int ch  = wave * (BM / 32) + p;
                int row = ch * 8 + subrow;
                gld_lds16(Ab + (size_t)(row0 + row) * K + k0 + swz, &As[ch * 512]);
            }
        }
        __syncthreads();
        #pragma unroll
        for (int kk = 0; kk < BK; kk += 32) {
            const int sg = ((((kk >> 3) + quad) ^ l7) << 3);  // swizzled read col
            short8 af[WM], bf[WN];
            #pragma unroll
            for (int i = 0; i < WM; i++) {
                int row = wr + i * 16 + l15;
                af[i] = AF32 ? *(const short8*)&As[row * LDTA + kk + quad * 8]
                             : *(const short8*)&As[row * 64 + sg];
            }
            #pragma unroll
            for (int j = 0; j < WN; j++) {
                int row = wc + j * 16 + l15;
                bf[j] = *(const short8*)&Bs[row * 64 + sg];
            }
            #pragma unroll
            for (int i = 0; i < WM; i++)
                #pragma unroll
                for (int j = 0; j < WN; j++)
                    acc[i][j] = __builtin_amdgcn_mfma_f32_16x16x32_bf16(af[i], bf[j], acc[i][j], 0, 0, 0);
        }
        __syncthreads();
    }

    // epilogue: C/D layout col=lane&15, row=quad*4+reg
    #pragma unroll
    for (int i = 0; i < WM; i++)
        #pragma unroll
        for (int j = 0; j < WN; j++)
            #pragma unroll
            for (int rr = 0; rr < 4; rr++) {
                int grow = row0 + wr + i * 16 + quad * 4 + rr;
                int gcol = col0 + wc + j * 16 + l15;
                if (grow < M) C[(size_t)grow * N + gcol] = f2bf(acc[i][j][rr]);
            }
}

// ---------------------------------------------------------------- SpMM 1
// wave per row; lane covers dims [lane*4, lane*4+4). Edge loop unrolled x4:
// 4 independent 512B gathers in flight to break the latency chain.
__global__ __launch_bounds__(256) void spmm1_k(const int* __restrict__ row_ptr,
                                               const int* __restrict__ col_s,
                                               const float* __restrict__ val_s,
                                               const ushort* __restrict__ h0,
                                               const float* __restrict__ b1,
                                               ushort* __restrict__ h) {
    int wave = threadIdx.x >> 6;
    int lane = threadIdx.x & 63;
    int r = blockIdx.x * 4 + wave;
    if (r >= N_NODES) return;
    int s = row_ptr[r];
    int e = row_ptr[r + 1];
    const ushort* hp = h0 + (size_t)lane * 4;
    float a0 = 0.f, a1 = 0.f, a2 = 0.f, a3 = 0.f;
    int i = s;
    for (; i + 4 <= e; i += 4) {
        int c0 = col_s[i];
        int c1 = col_s[i + 1];
        int c2 = col_s[i + 2];
        int c3 = col_s[i + 3];
        float v0 = val_s[i];
        float v1 = val_s[i + 1];
        float v2 = val_s[i + 2];
        float v3 = val_s[i + 3];
        ushort4 q0 = *(const ushort4*)(hp + (size_t)c0 * HID);
        ushort4 q1 = *(const ushort4*)(hp + (size_t)c1 * HID);
        ushort4 q2 = *(const ushort4*)(hp + (size_t)c2 * HID);
        ushort4 q3 = *(const ushort4*)(hp + (size_t)c3 * HID);
        a0 += v0 * bf2f(q0.x); a1 += v0 * bf2f(q0.y); a2 += v0 * bf2f(q0.z); a3 += v0 * bf2f(q0.w);
        a0 += v1 * bf2f(q1.x); a1 += v1 * bf2f(q1.y); a2 += v1 * bf2f(q1.z); a3 += v1 * bf2f(q1.w);
        a0 += v2 * bf2f(q2.x); a1 += v2 * bf2f(q2.y); a2 += v2 * bf2f(q2.z); a3 += v2 * bf2f(q2.w);
        a0 += v3 * bf2f(q3.x); a1 += v3 * bf2f(q3.y); a2 += v3 * bf2f(q3.z); a3 += v3 * bf2f(q3.w);
    }
    for (; i < e; i++) {
        int c = col_s[i];
        float v = val_s[i];
        ushort4 q = *(const ushort4*)(hp + (size_t)c * HID);
        a0 += v * bf2f(q.x); a1 += v * bf2f(q.y); a2 += v * bf2f(q.z); a3 += v * bf2f(q.w);
    }
    float4 bb = *(const float4*)(b1 + lane * 4);
    a0 += bb.x; a1 += bb.y; a2 += bb.z; a3 += bb.w;
    a0 = fmaxf(a0, 0.f); a1 = fmaxf(a1, 0.f); a2 = fmaxf(a2, 0.f); a3 = fmaxf(a3, 0.f);
    ushort4 o;
    o.x = f2bf(a0); o.y = f2bf(a1); o.z = f2bf(a2); o.w = f2bf(a3);
    *(ushort4*)(h + (size_t)r * HID + lane * 4) = o;
}

// ---------------------------------------------------------------- SpMM 2
__global__ __launch_bounds__(256) void spmm2_k(const int* __restrict__ row_ptr,
                                               const int* __restrict__ col_s,
                                               const float* __restrict__ val_s,
                                               const ushort* __restrict__ h2,
                                               const float* __restrict__ b2,
                                               float* __restrict__ out) {
    int wave = threadIdx.x >> 6;
    int lane = threadIdx.x & 63;
    int r = blockIdx.x * 4 + wave;
    if (r >= N_NODES) return;
    int s = row_ptr[r];
    int e = row_ptr[r + 1];
    int slot = lane >> 4;   // 0..3
    int dg   = lane & 15;   // dim group, 4 dims
    float a0 = 0.f, a1 = 0.f, a2 = 0.f, a3 = 0.f;
    const ushort* hp = h2 + (size_t)dg * 4;
    for (int i = s + slot; i < e; i += 4) {
        int c = col_s[i];
        float v = val_s[i];
        ushort4 q = *(const ushort4*)(hp + (size_t)c * OUTD);
        a0 += v * bf2f(q.x);
        a1 += v * bf2f(q.y);
        a2 += v * bf2f(q.z);
        a3 += v * bf2f(q.w);
    }
    #pragma unroll
    for (int m = 16; m < 64; m <<= 1) {
        a0 += __shfl_xor(a0, m, 64);
        a1 += __shfl_xor(a1, m, 64);
        a2 += __shfl_xor(a2, m, 64);
        a3 += __shfl_xor(a3, m, 64);
    }
    if (slot == 0) {
        float4 bb = *(const float4*)(b2 + dg * 4);
        float4 o;
        o.x = a0 + bb.x; o.y = a1 + bb.y; o.z = a2 + bb.z; o.w = a3 + bb.w;
        *(float4*)(out + (size_t)r * OUTD + dg * 4) = o;
    }
}

// ---------------------------------------------------------------- launch
extern "C" void kernel_launch(void* const* d_in, const int* in_sizes, int n_in,
                              void* d_out, int out_size, void* d_ws, size_t ws_size,
                              hipStream_t stream) {
    const float* x    = (const float*)d_in[0];
    const int*   rows = (const int*)d_in[1];
    const int*   cols = (const int*)d_in[2];
    const float* vals = (const float*)d_in[3];
    const float* W1   = (const float*)d_in[4];
    const float* b1   = (const float*)d_in[5];
    const float* W2   = (const float*)d_in[6];
    const float* b2   = (const float*)d_in[7];
    float* out = (float*)d_out;

    char* ws = (char*)d_ws;
    size_t off = 0;
    auto alloc = [&](size_t bytes) {
        char* p = ws + off;
        off = (off + bytes + 255) & ~(size_t)255;
        return p;
    };
    ushort* w1t   = (ushort*)alloc((size_t)HID * IN_DIM * 2);
    ushort* w2t   = (ushort*)alloc((size_t)OUTD * HID * 2);
    ushort* h0    = (ushort*)alloc((size_t)N_NODES * HID * 2);
    ushort* h     = (ushort*)alloc((size_t)M_PAD * HID * 2);     // padded rows
    ushort* h2    = (ushort*)alloc((size_t)N_NODES * OUTD * 2);
    int*    cnt   = (int*)alloc((PAD_N) * 4);
    int*    rptr  = (int*)alloc((PAD_N + 1) * 4);
    int*    bsum  = (int*)alloc(SCAN_NB * 4);
    int*    boff  = (int*)alloc(SCAN_NB * 4);
    int*    rank  = (int*)alloc((size_t)E_EDGES * 4);
    int*    col_s = (int*)alloc((size_t)E_EDGES * 4);
    float*  val_s = (float*)alloc((size_t)E_EDGES * 4);

    // init: zero cnt + weight transpose/convert (fused, independent work)
    {
        const int work = IN_DIM * HID + HID * OUTD;  // 147456 > PAD_N
        init_k<<<(work + 255) / 256, 256, 0, stream>>>(W1, W2, w1t, w2t, cnt);
    }
    // CSR build (reused by both SpMMs)
    hist_k<<<(E_EDGES + 255) / 256, 256, 0, stream>>>(rows, cnt, rank);
    scan_part_k<<<SCAN_NB, 256, 0, stream>>>(cnt, bsum);
    scan_bsum_k<<<1, 64, 0, stream>>>(bsum, boff);
    scan_final_k<<<SCAN_NB, 256, 0, stream>>>(cnt, boff, rptr);
    scatter_k<<<(E_EDGES + 255) / 256, 256, 0, stream>>>(rows, cols, vals, rptr, rank, col_s, val_s);

    // layer 1: h0 = x @ W1, BM=64 x BN=256 single N-pass (A converted once)
    gemm_bf16<true, 64, 256, 1, 4, 4, 4><<<dim3(HID / 256, M_PAD / 64), 256, 0, stream>>>(
        x, nullptr, w1t, h0, N_NODES, HID, IN_DIM);
    spmm1_k<<<(N_NODES + 3) / 4, 256, 0, stream>>>(rptr, col_s, val_s, h0, b1, h);

    // layer 2: A (bf16 h) and B both DMA-staged; LDS 24KB -> 6 blocks/CU
    gemm_bf16<false, 128, 64, 4, 1, 2, 4><<<dim3(OUTD / 64, M_PAD / 128), 256, 0, stream>>>(
        nullptr, h, w2t, h2, N_NODES, OUTD, HID);
    spmm2_k<<<(N_NODES + 3) / 4, 256, 0, stream>>>(rptr, col_s, val_s, h2, b2, out);
}

// Round 6
// 356.336 us; speedup vs baseline: 1.1658x; 1.0047x over previous
//
#include <hip/hip_runtime.h>

#define N_NODES 50000
#define E_EDGES 800000
#define IN_DIM  512
#define HID     256
#define OUTD    64

#define M_PAD   50048              // 391 * 128 (also 782 * 64)
#define SCAN_NB  49                // ceil(50000/1024)
#define PAD_N    (SCAN_NB * 1024)  // 50176

typedef unsigned int uint;
typedef unsigned short ushort;

using short8 = __attribute__((ext_vector_type(8))) short;
using f32x4  = __attribute__((ext_vector_type(4))) float;

__device__ __forceinline__ ushort f2bf(float f) {
    union { float f; uint u; } v; v.f = f;
    uint u = v.u;
    uint r = (u + 0x7FFFu + ((u >> 16) & 1u)) >> 16;  // RNE
    return (ushort)r;
}

__device__ __forceinline__ float bf2f(ushort h) {
    union { uint u; float f; } v; v.u = ((uint)h) << 16;
    return v.f;
}

// HW packed convert: dst = {bf16(a) | bf16(b)<<16}, RNE — 1 instr per 2 elems
__device__ __forceinline__ uint pk2(float a, float b) {
    uint r;
    asm("v_cvt_pk_bf16_f32 %0, %1, %2" : "=v"(r) : "v"(a), "v"(b));
    return r;
}

// 16B global -> LDS DMA. LDS dest is wave-uniform base + lane*16 (HW rule);
// global source is per-lane (pre-swizzled-source pattern).
__device__ __forceinline__ void gld_lds16(const ushort* g, ushort* l) {
    __builtin_amdgcn_global_load_lds(
        (const __attribute__((address_space(1))) unsigned int*)g,
        (__attribute__((address_space(3))) unsigned int*)l, 16, 0, 0);
}

// ---------------------------------------------------------------- init
// fused: zero cnt[] + transpose/convert W1,W2 -> bf16 [N,K] (independent work)
__global__ __launch_bounds__(256) void init_k(const float* __restrict__ W1,
                                              const float* __restrict__ W2,
                                              ushort* __restrict__ W1t,
                                              ushort* __restrict__ W2t,
                                              int* __restrict__ cnt) {
    int i = blockIdx.x * 256 + threadIdx.x;
    if (i < PAD_N) cnt[i] = 0;
    const int N1 = IN_DIM * HID;  // 131072
    if (i < N1) {
        int n = i / IN_DIM;
        int k = i - n * IN_DIM;
        W1t[i] = f2bf(W1[(size_t)k * HID + n]);
    } else {
        int j = i - N1;
        if (j < HID * OUTD) {
            int n = j / HID;
            int k = j - n * HID;
            W2t[j] = f2bf(W2[(size_t)k * OUTD + n]);
        }
    }
}

// ---------------------------------------------------------------- CSR build
// hist + per-edge rank in one pass: rank[e] = position of edge within its row
__global__ void hist_k(const int* __restrict__ rows, int* __restrict__ cnt,
                       int* __restrict__ rank) {
    int e = blockIdx.x * 256 + threadIdx.x;
    if (e < E_EDGES) rank[e] = atomicAdd(&cnt[rows[e]], 1);
}

__global__ __launch_bounds__(256) void scan_part_k(const int* __restrict__ cnt,
                                                   int* __restrict__ bsum) {
    __shared__ int wsum[4];
    int tid  = threadIdx.x;
    int lane = tid & 63;
    int wave = tid >> 6;
    int4 q = *(const int4*)(cnt + blockIdx.x * 1024 + tid * 4);
    int s = q.x + q.y + q.z + q.w;
    #pragma unroll
    for (int d = 32; d > 0; d >>= 1) s += __shfl_down(s, d, 64);
    if (lane == 0) wsum[wave] = s;
    __syncthreads();
    if (tid == 0) bsum[blockIdx.x] = wsum[0] + wsum[1] + wsum[2] + wsum[3];
}

__global__ __launch_bounds__(64) void scan_bsum_k(const int* __restrict__ bsum,
                                                  int* __restrict__ boff) {
    int tid = threadIdx.x;
    int v = (tid < SCAN_NB) ? bsum[tid] : 0;
    int incl = v;
    #pragma unroll
    for (int d = 1; d < 64; d <<= 1) {
        int t = __shfl_up(incl, d, 64);
        if (tid >= d) incl += t;
    }
    if (tid < SCAN_NB) boff[tid] = incl - v;
}

__global__ __launch_bounds__(256) void scan_final_k(const int* __restrict__ cnt,
                                                    const int* __restrict__ boff,
                                                    int* __restrict__ row_ptr) {
    __shared__ int wsum[4];
    __shared__ int woff[4];
    int tid  = threadIdx.x;
    int lane = tid & 63;
    int wave = tid >> 6;
    int base = blockIdx.x * 1024 + tid * 4;
    int4 q = *(const int4*)(cnt + base);
    int s = q.x + q.y + q.z + q.w;
    int incl = s;
    #pragma unroll
    for (int d = 1; d < 64; d <<= 1) {
        int t = __shfl_up(incl, d, 64);
        if (lane >= d) incl += t;
    }
    if (lane == 63) wsum[wave] = incl;
    __syncthreads();
    if (tid == 0) {
        int run = 0;
        #pragma unroll
        for (int w = 0; w < 4; w++) { woff[w] = run; run += wsum[w]; }
    }
    __syncthreads();
    int off = boff[blockIdx.x] + woff[wave] + (incl - s);
    int4 o;
    o.x = off;
    o.y = off + q.x;
    o.z = o.y + q.y;
    o.w = o.z + q.z;
    *(int4*)(row_ptr + base) = o;
    if (blockIdx.x == 0 && tid == 0) row_ptr[N_NODES] = E_EDGES;
}

// atomic-free scatter: slot = row_ptr[row] + precomputed rank
__global__ void scatter_k(const int* __restrict__ rows, const int* __restrict__ cols,
                          const float* __restrict__ vals, const int* __restrict__ rptr,
                          const int* __restrict__ rank,
                          int* __restrict__ col_s, float* __restrict__ val_s) {
    int e = blockIdx.x * 256 + threadIdx.x;
    if (e < E_EDGES) {
        int p = rptr[rows[e]] + rank[e];
        col_s[p] = cols[e];
        val_s[p] = vals[e];
    }
}

// ---------------------------------------------------------------- GEMM bf16
// C[M,N](bf16) = A[M,K] * Bt[N,K](bf16 = B^T). Double-buffered LDS, ONE
// barrier per K-step:
//   STAGE(buf^1, k+1)  -> A loads first (vmcnt(4) wait, not a drain), B DMA
//                         fire-and-forget, A cvt+ds_write (regs die here)
//   COMPUTE(buf)       -> MFMA on the other buffer
//   __syncthreads()    -> drains DMA(k+1) + publishes buf^1 + retires buf
// No registers live across MFMA -> no spill (rounds 1/3/4 lesson).
// DMA tiles are linear with both-sides XOR swizzle (rule #21, verified r5):
//   store: source col-group = (lane&7) ^ ((lane>>3)&7)
//   read:  col slot ((kk>>3)+quad) ^ (row&7)  [row&7 == lane&7 on reads]
// L1's A stays fp32->bf16 register-convert path (padded 144B rows).
template <bool AF32, int BM, int BN, int RW, int CW, int WM, int WN>
__global__ __launch_bounds__(256) void gemm_bf16(const float* __restrict__ Af,
                                                 const ushort* __restrict__ Ab,
                                                 const ushort* __restrict__ Bt,
                                                 ushort* __restrict__ C,
                                                 int M, int N, int K) {
    constexpr int BK   = 64;
    constexpr int LDTA = AF32 ? 72 : 64;      // A rows: padded (reg) / linear (DMA)
    constexpr int ACH  = (BM * BK / 8) / 256; // reg-path chunks per thread
    __shared__ ushort As[2 * BM * LDTA];
    __shared__ ushort Bs[2 * BN * 64];

    const int tid  = threadIdx.x;
    const int lane = tid & 63;
    const int wave = tid >> 6;
    const int quad = lane >> 4;
    const int l15  = lane & 15;
    const int l7   = lane & 7;

    const int col0 = blockIdx.x * BN;
    const int row0 = blockIdx.y * BM;

    const int wr = (wave % RW) * (WM * 16);
    const int wc = (wave / RW) * (WN * 16);

    const int swz    = (l7 ^ ((lane >> 3) & 7)) << 3;  // source col offset (ushorts)
    const int subrow = lane >> 3;                      // row within 8-row chunk

    f32x4 acc[WM][WN] = {};

#define STAGE(BUF, KOFF)                                                      \
    {                                                                         \
        ushort* Aw = As + (BUF) * BM * LDTA;                                  \
        ushort* Bw = Bs + (BUF) * BN * 64;                                    \
        if constexpr (AF32) {                                                 \
            float4 pf[2 * ACH];                                               \
            _Pragma("unroll")                                                 \
            for (int p = 0; p < ACH; p++) {   /* A loads FIRST (oldest) */    \
                int c = tid + p * 256;                                        \
                int row = c >> 3, sub = c & 7;                                \
                int gr = row0 + row;                                          \
                gr = gr < M ? gr : M - 1;                                     \
                const float* pa = Af + (size_t)gr * K + (KOFF) + sub * 8;     \
                pf[2 * p]     = *(const float4*)pa;                           \
                pf[2 * p + 1] = *(const float4*)(pa + 4);                     \
            }                                                                 \
            _Pragma("unroll")                                                 \
            for (int p = 0; p < BN / 32; p++) {  /* B DMA: fire-and-forget */ \
                int ch  = wave * (BN / 32) + p;                               \
                int row = ch * 8 + subrow;                                    \
                gld_lds16(Bt + (size_t)(col0 + row) * K + (KOFF) + swz,       \
                          Bw + ch * 512);                                     \
            }                                                                 \
            _Pragma("unroll")                                                 \
            for (int p = 0; p < ACH; p++) {   /* waits vmcnt(B-count) only */ \
                int c = tid + p * 256;                                        \
                int row = c >> 3, sub = c & 7;                                \
                float4 f0 = pf[2 * p];                                        \
                float4 f1 = pf[2 * p + 1];                                    \
                uint4 q;                                                      \
                q.x = pk2(f0.x, f0.y);                                        \
                q.y = pk2(f0.z, f0.w);                                        \
                q.z = pk2(f1.x, f1.y);                                        \
                q.w = pk2(f1.z, f1.w);                                        \
                *(uint4*)&Aw[row * LDTA + sub * 8] = q;                       \
            }                                                                 \
        } else {                                                              \
            _Pragma("unroll")                                                 \
            for (int p = 0; p < BM / 32; p++) {                               \
                int ch  = wave * (BM / 32) + p;                               \
                int row = ch * 8 + subrow;                                    \
                gld_lds16(Ab + (size_t)(row0 + row) * K + (KOFF) + swz,       \
                          Aw + ch * 512);                                     \
            }                                                                 \
            _Pragma("unroll")                                                 \
            for (int p = 0; p < BN / 32; p++) {                               \
                int ch  = wave * (BN / 32) + p;                               \
                int row = ch * 8 + subrow;                                    \
                gld_lds16(Bt + (size_t)(col0 + row) * K + (KOFF) + swz,       \
                          Bw + ch * 512);                                     \
            }                                                                 \
        }                                                                     \
    }

#define COMPUTE(BUF)                                                          \
    {                                                                         \
        const ushort* Ar = As + (BUF) * BM * LDTA;                            \
        const ushort* Br = Bs + (BUF) * BN * 64;                              \
        _Pragma("unroll")                                                     \
        for (int kk = 0; kk < BK; kk += 32) {                                 \
            const int sg = ((((kk >> 3) + quad) ^ l7) << 3);                  \
            short8 af[WM], bf[WN];                                            \
            _Pragma("unroll")                                                 \
            for (int i = 0; i < WM; i++) {                                    \
                int row = wr + i * 16 + l15;                                  \
                af[i] = AF32 ? *(const short8*)&Ar[row * LDTA + kk + quad * 8]\
                             : *(const short8*)&Ar[row * 64 + sg];            \
            }                                                                 \
            _Pragma("unroll")                                                 \
            for (int j = 0; j < WN; j++) {                                    \
                int row = wc + j * 16 + l15;                                  \
                bf[j] = *(const short8*)&Br[row * 64 + sg];                   \
            }                                                                 \
            _Pragma("unroll")                                                 \
            for (int i = 0; i < WM; i++)                                      \
                _Pragma("unroll")                                             \
                for (int j = 0; j < WN; j++)                                  \
                    acc[i][j] = __builtin_amdgcn_mfma_f32_16x16x32_bf16(af[i], bf[j], acc[i][j], 0, 0, 0); \
        }                                                                     \
    }

    STAGE(0, 0)
    __syncthreads();
    int o = 0;
    for (int k0 = 0; k0 < K; k0 += BK) {
        if (k0 + BK < K) STAGE(o ^ 1, k0 + BK)   // prefetch into other buffer
        COMPUTE(o)
        __syncthreads();   // drain DMA + publish buf^1 + retire buf
        o ^= 1;
    }

#undef STAGE
#undef COMPUTE

    // epilogue: C/D layout col=lane&15, row=quad*4+reg
    #pragma unroll
    for (int i = 0; i < WM; i++)
        #pragma unroll
        for (int j = 0; j < WN; j++)
            #pragma unroll
            for (int rr = 0; rr < 4; rr++) {
                int grow = row0 + wr + i * 16 + quad * 4 + rr;
                int gcol = col0 + wc + j * 16 + l15;
                if (grow < M) C[(size_t)grow * N + gcol] = f2bf(acc[i][j][rr]);
            }
}

// ---------------------------------------------------------------- SpMM 1
// wave per row; lane covers dims [lane*4, lane*4+4). Edge loop unrolled x4:
// 4 independent 512B gathers in flight to break the latency chain.
__global__ __launch_bounds__(256) void spmm1_k(const int* __restrict__ row_ptr,
                                               const int* __restrict__ col_s,
                                               const float* __restrict__ val_s,
                                               const ushort* __restrict__ h0,
                                               const float* __restrict__ b1,
                                               ushort* __restrict__ h) {
    int wave = threadIdx.x >> 6;
    int lane = threadIdx.x & 63;
    int r = blockIdx.x * 4 + wave;
    if (r >= N_NODES) return;
    int s = row_ptr[r];
    int e = row_ptr[r + 1];
    const ushort* hp = h0 + (size_t)lane * 4;
    float a0 = 0.f, a1 = 0.f, a2 = 0.f, a3 = 0.f;
    int i = s;
    for (; i + 4 <= e; i += 4) {
        int c0 = col_s[i];
        int c1 = col_s[i + 1];
        int c2 = col_s[i + 2];
        int c3 = col_s[i + 3];
        float v0 = val_s[i];
        float v1 = val_s[i + 1];
        float v2 = val_s[i + 2];
        float v3 = val_s[i + 3];
        ushort4 q0 = *(const ushort4*)(hp + (size_t)c0 * HID);
        ushort4 q1 = *(const ushort4*)(hp + (size_t)c1 * HID);
        ushort4 q2 = *(const ushort4*)(hp + (size_t)c2 * HID);
        ushort4 q3 = *(const ushort4*)(hp + (size_t)c3 * HID);
        a0 += v0 * bf2f(q0.x); a1 += v0 * bf2f(q0.y); a2 += v0 * bf2f(q0.z); a3 += v0 * bf2f(q0.w);
        a0 += v1 * bf2f(q1.x); a1 += v1 * bf2f(q1.y); a2 += v1 * bf2f(q1.z); a3 += v1 * bf2f(q1.w);
        a0 += v2 * bf2f(q2.x); a1 += v2 * bf2f(q2.y); a2 += v2 * bf2f(q2.z); a3 += v2 * bf2f(q2.w);
        a0 += v3 * bf2f(q3.x); a1 += v3 * bf2f(q3.y); a2 += v3 * bf2f(q3.z); a3 += v3 * bf2f(q3.w);
    }
    for (; i < e; i++) {
        int c = col_s[i];
        float v = val_s[i];
        ushort4 q = *(const ushort4*)(hp + (size_t)c * HID);
        a0 += v * bf2f(q.x); a1 += v * bf2f(q.y); a2 += v * bf2f(q.z); a3 += v * bf2f(q.w);
    }
    float4 bb = *(const float4*)(b1 + lane * 4);
    a0 += bb.x; a1 += bb.y; a2 += bb.z; a3 += bb.w;
    a0 = fmaxf(a0, 0.f); a1 = fmaxf(a1, 0.f); a2 = fmaxf(a2, 0.f); a3 = fmaxf(a3, 0.f);
    ushort4 o;
    o.x = f2bf(a0); o.y = f2bf(a1); o.z = f2bf(a2); o.w = f2bf(a3);
    *(ushort4*)(h + (size_t)r * HID + lane * 4) = o;
}

// ---------------------------------------------------------------- SpMM 2
__global__ __launch_bounds__(256) void spmm2_k(const int* __restrict__ row_ptr,
                                               const int* __restrict__ col_s,
                                               const float* __restrict__ val_s,
                                               const ushort* __restrict__ h2,
                                               const float* __restrict__ b2,
                                               float* __restrict__ out) {
    int wave = threadIdx.x >> 6;
    int lane = threadIdx.x & 63;
    int r = blockIdx.x * 4 + wave;
    if (r >= N_NODES) return;
    int s = row_ptr[r];
    int e = row_ptr[r + 1];
    int slot = lane >> 4;   // 0..3
    int dg   = lane & 15;   // dim group, 4 dims
    float a0 = 0.f, a1 = 0.f, a2 = 0.f, a3 = 0.f;
    const ushort* hp = h2 + (size_t)dg * 4;
    for (int i = s + slot; i < e; i += 4) {
        int c = col_s[i];
        float v = val_s[i];
        ushort4 q = *(const ushort4*)(hp + (size_t)c * OUTD);
        a0 += v * bf2f(q.x);
        a1 += v * bf2f(q.y);
        a2 += v * bf2f(q.z);
        a3 += v * bf2f(q.w);
    }
    #pragma unroll
    for (int m = 16; m < 64; m <<= 1) {
        a0 += __shfl_xor(a0, m, 64);
        a1 += __shfl_xor(a1, m, 64);
        a2 += __shfl_xor(a2, m, 64);
        a3 += __shfl_xor(a3, m, 64);
    }
    if (slot == 0) {
        float4 bb = *(const float4*)(b2 + dg * 4);
        float4 o;
        o.x = a0 + bb.x; o.y = a1 + bb.y; o.z = a2 + bb.z; o.w = a3 + bb.w;
        *(float4*)(out + (size_t)r * OUTD + dg * 4) = o;
    }
}

// ---------------------------------------------------------------- launch
extern "C" void kernel_launch(void* const* d_in, const int* in_sizes, int n_in,
                              void* d_out, int out_size, void* d_ws, size_t ws_size,
                              hipStream_t stream) {
    const float* x    = (const float*)d_in[0];
    const int*   rows = (const int*)d_in[1];
    const int*   cols = (const int*)d_in[2];
    const float* vals = (const float*)d_in[3];
    const float* W1   = (const float*)d_in[4];
    const float* b1   = (const float*)d_in[5];
    const float* W2   = (const float*)d_in[6];
    const float* b2   = (const float*)d_in[7];
    float* out = (float*)d_out;

    char* ws = (char*)d_ws;
    size_t off = 0;
    auto alloc = [&](size_t bytes) {
        char* p = ws + off;
        off = (off + bytes + 255) & ~(size_t)255;
        return p;
    };
    ushort* w1t   = (ushort*)alloc((size_t)HID * IN_DIM * 2);
    ushort* w2t   = (ushort*)alloc((size_t)OUTD * HID * 2);
    ushort* h0    = (ushort*)alloc((size_t)N_NODES * HID * 2);
    ushort* h     = (ushort*)alloc((size_t)M_PAD * HID * 2);     // padded rows
    ushort* h2    = (ushort*)alloc((size_t)N_NODES * OUTD * 2);
    int*    cnt   = (int*)alloc((PAD_N) * 4);
    int*    rptr  = (int*)alloc((PAD_N + 1) * 4);
    int*    bsum  = (int*)alloc(SCAN_NB * 4);
    int*    boff  = (int*)alloc(SCAN_NB * 4);
    int*    rank  = (int*)alloc((size_t)E_EDGES * 4);
    int*    col_s = (int*)alloc((size_t)E_EDGES * 4);
    float*  val_s = (float*)alloc((size_t)E_EDGES * 4);

    // init: zero cnt + weight transpose/convert (fused, independent work)
    {
        const int work = IN_DIM * HID + HID * OUTD;  // 147456 > PAD_N
        init_k<<<(work + 255) / 256, 256, 0, stream>>>(W1, W2, w1t, w2t, cnt);
    }
    // CSR build (reused by both SpMMs)
    hist_k<<<(E_EDGES + 255) / 256, 256, 0, stream>>>(rows, cnt, rank);
    scan_part_k<<<SCAN_NB, 256, 0, stream>>>(cnt, bsum);
    scan_bsum_k<<<1, 64, 0, stream>>>(bsum, boff);
    scan_final_k<<<SCAN_NB, 256, 0, stream>>>(cnt, boff, rptr);
    scatter_k<<<(E_EDGES + 255) / 256, 256, 0, stream>>>(rows, cols, vals, rptr, rank, col_s, val_s);

    // layer 1: h0 = x @ W1. BM=64 x BN=128 dbuf -> grid 2x782 = 1564 blocks
    gemm_bf16<true, 64, 128, 1, 4, 4, 2><<<dim3(HID / 128, M_PAD / 64), 256, 0, stream>>>(
        x, nullptr, w1t, h0, N_NODES, HID, IN_DIM);
    spmm1_k<<<(N_NODES + 3) / 4, 256, 0, stream>>>(rptr, col_s, val_s, h0, b1, h);

    // layer 2: BM=64 x BN=64 dbuf, all-DMA -> 782 blocks, LDS 32KB (5/CU)
    gemm_bf16<false, 64, 64, 2, 2, 2, 2><<<dim3(OUTD / 64, M_PAD / 64), 256, 0, stream>>>(
        nullptr, h, w2t, h2, N_NODES, OUTD, HID);
    spmm2_k<<<(N_NODES + 3) / 4, 256, 0, stream>>>(rptr, col_s, val_s, h2, b2, out);
}